// Round 1
// 167.721 us; speedup vs baseline: 1.1376x; 1.1376x over previous
//
#include <hip/hip_runtime.h>
#include <hip/hip_bf16.h>
#include <math.h>

typedef __attribute__((ext_vector_type(8))) short bf16x8;
typedef __attribute__((ext_vector_type(4))) float f32x4;

#define NQ 16384
#define NN 32
#define FI 128
#define FO 256
#define KPN 15
#define OD 42
#define INV_EXT 0.5f

// ws layout (bytes)
#define WS_FP1    0u                        // [NQ][128] u32 pair-frag hi/lo  = 8 MB
#define WS_FP2    (8u * 1024u * 1024u)      // [NQ][64]  u32 pair-frag hi     = 4 MB
#define WS_BSW    (12u * 1024u * 1024u)     // 1 MB
#define WS_DWBH   (13u * 1024u * 1024u)     // 196,608
#define WS_DWBL   (WS_DWBH + 196608u)       // 196,608
#define WS_DEFKP  (14u * 1024u * 1024u)     // 16384*45*4 = 2.95 MB

static __device__ __forceinline__ unsigned short f2bf(float x) {
    union { __hip_bfloat16 h; unsigned short u; } cv;
    cv.h = __float2bfloat16(x);
    return cv.u;
}
static __device__ __forceinline__ float bf2f(unsigned short h) {
    union { unsigned int u; float f; } cv;
    cv.u = ((unsigned int)h) << 16;
    return cv.f;
}

union U8 { unsigned short u[8]; bf16x8 v; };

// ------------------------- fused pre-kernel (unchanged) -------------------------
__global__ void pre_all(const float* __restrict__ feat,
                        unsigned int* __restrict__ fp1, unsigned int* __restrict__ fp2,
                        const float* __restrict__ w, unsigned short* __restrict__ Bsw,
                        const float* __restrict__ dw,
                        unsigned short* __restrict__ dhi, unsigned short* __restrict__ dlo)
{
    const int b = blockIdx.x, t = threadIdx.x;
    if (b < 4096) {
        const int tid = b * 256 + t;          // 1,048,576 total = NQ*64
        const int s = tid >> 6, r = tid & 63;
        const int fp = r >> 4, low = r & 15;
        const float a = feat[s * FI + fp * 32 + low];
        const float c = feat[s * FI + fp * 32 + 16 + low];
        const unsigned short ha = f2bf(a), hc = f2bf(c);
        const unsigned int w0 = (unsigned int)ha | ((unsigned int)hc << 16);
        const unsigned int w1 = (unsigned int)f2bf(a - bf2f(ha)) |
                                ((unsigned int)f2bf(c - bf2f(hc)) << 16);
        uint2 pr; pr.x = w0; pr.y = w1;
        *(uint2*)&fp1[s * 128 + fp * 32 + low * 2] = pr;
        fp2[s * 64 + fp * 16 + low] = w0;
    } else if (b < 4096 + 256) {
        const int tid = (b - 4096) * 256 + t; // 65536 total
        const int lane = tid & 63;
        const int kt   = (tid >> 6) & 63;
        const int nt   = tid >> 12;
        const int n    = nt * 16 + (lane & 15);
        const int kbase = kt * 32 + (lane >> 4) * 8;
        unsigned int p[4];
        #pragma unroll
        for (int jj = 0; jj < 4; jj++) {
            unsigned int lo, hi;
            {
                const int kk = kbase + 2 * jj;
                const int f = kk >> 4, k = kk & 15;
                lo = (k < KPN) ? f2bf(w[(k * FI + f) * FO + n]) : 0u;
            }
            {
                const int kk = kbase + 2 * jj + 1;
                const int f = kk >> 4, k = kk & 15;
                hi = (k < KPN) ? f2bf(w[(k * FI + f) * FO + n]) : 0u;
            }
            p[jj] = lo | (hi << 16);
        }
        unsigned int* op = (unsigned int*)&Bsw[tid * 8];
        op[0] = p[0]; op[1] = p[1]; op[2] = p[2]; op[3] = p[3];
    } else {
        const int tid = (b - 4352) * 256 + t; // 12288 total
        const int lane = tid & 63;
        const int kt   = (tid >> 6) & 63;
        const int nt   = tid >> 12;
        const int o    = nt * 16 + (lane & 15);
        const int kbase = kt * 32 + (lane >> 4) * 8;
        #pragma unroll
        for (int j = 0; j < 8; j++) {
            const int kf = kbase + j;
            const int f = kf >> 4, k = kf & 15;
            float v = (k < KPN && o < OD) ? dw[(k * FI + f) * OD + o] : 0.f;
            unsigned short h = f2bf(v);
            dhi[tid * 8 + j] = h;
            dlo[tid * 8 + j] = f2bf(v - bf2f(h));
        }
    }
}

// ------------------------- stage 1: offsets via split-bf16 MFMA -------------------------
// E=16 queries/block, 512 threads (8 waves). f-chunked (4 chunks of 32 features)
// so the wf0 staging buffer is 16 KB/array. LDS total ~44 KB.
// wfA chunk layout: element (e in [0,16), c_local in [0,512)):
//   cblk = c_local>>3 (0..63), slot = e ^ (cblk&15),
//   hw   = cblk*128 + slot*8 + (c_local&7)
// -> phase-C reads (lane=(quad,low), 16B each) hit 16 distinct contiguous slots
//    per 16-lane group: bank-conflict-free. Writes are ~4-way (rare path).
__global__ __launch_bounds__(512, 4)
void k1_offsets(const float* __restrict__ query, const float* __restrict__ support,
                const int* __restrict__ neighbors, const unsigned int* __restrict__ fp1,
                const float* __restrict__ kpoints,
                const unsigned short* __restrict__ dwB_hi,
                const unsigned short* __restrict__ dwB_lo,
                const float* __restrict__ bias, float* __restrict__ defkp)
{
    __shared__ unsigned short wfA_hi[8192];             // 16 KB
    __shared__ unsigned short wfA_lo[8192];             // 16 KB
    __shared__ float relx[512], rely[512], relz[512];   // 6144 B
    __shared__ int   nbr_s[512];                        // 2048 B
    __shared__ float kp_s[48];                          // 192 B
    __shared__ f32x4 cred[3 * 64];                      // 3072 B

    const int t = threadIdx.x;
    const int qbase = blockIdx.x * 16;
    if (t < 45) kp_s[t] = kpoints[t];
    if (t >= 45 && t < 48) kp_s[t] = 0.f;

    {   // 512 threads cover 16 queries x 32 neighbors exactly
        const int e = t >> 5, n = t & 31;
        const int q = qbase + e;
        const int idx = neighbors[q * NN + n];
        nbr_s[t] = idx;
        relx[t] = support[idx * 3 + 0] - query[q * 3 + 0];
        rely[t] = support[idx * 3 + 1] - query[q * 3 + 1];
        relz[t] = support[idx * 3 + 2] - query[q * 3 + 2];
    }
    __syncthreads();

    const int wave = t >> 6, lane = t & 63;
    const int quad = lane >> 4, low = lane & 15;
    const int ee0 = wave * 2;

    // hoisted split-bf16 A-fragments (w0^T) for this wave's two queries
    const int kb = (low < KPN) ? low * 3 : 0;
    const float kx = kp_s[kb + 0], ky = kp_s[kb + 1], kz = kp_s[kb + 2];
    U8 ah[2], al[2];
    #pragma unroll
    for (int ei = 0; ei < 2; ei++) {
        #pragma unroll
        for (int j = 0; j < 8; j++) {
            const int ni = (ee0 + ei) * 32 + quad * 8 + j;
            const float dx = relx[ni] - kx;
            const float dy = rely[ni] - ky;
            const float dz = relz[ni] - kz;
            const float d = sqrtf(dx * dx + dy * dy + dz * dz);
            float w = 1.0f - d * INV_EXT;
            w = (low < KPN && w > 0.f) ? w : 0.f;
            const unsigned short h = f2bf(w);
            ah[ei].u[j] = h;
            al[ei].u[j] = f2bf(w - bf2f(h));
        }
    }

    f32x4 acc = {0.f, 0.f, 0.f, 0.f};
    const int nt = wave >> 1, half = wave & 1;

    for (int c = 0; c < 4; c++) {
        // ---- phase B: wf0 chunk for f in [c*32, c*32+32), all 8 waves ----
        #pragma unroll
        for (int ei = 0; ei < 2; ei++) {
            const int ee = ee0 + ei;
            union { unsigned int u[4]; bf16x8 v; } bhA, blA, bhB, blB;
            #pragma unroll
            for (int jj = 0; jj < 4; jj++) {
                const int r0 = nbr_s[ee * 32 + quad * 8 + 2 * jj];
                const int r1 = nbr_s[ee * 32 + quad * 8 + 2 * jj + 1];
                const uint2 d0 = *(const uint2*)&fp1[r0 * 128 + c * 32 + low * 2];
                const uint2 d1 = *(const uint2*)&fp1[r1 * 128 + c * 32 + low * 2];
                bhA.u[jj] = __builtin_amdgcn_perm(d1.x, d0.x, 0x05040100u);
                bhB.u[jj] = __builtin_amdgcn_perm(d1.x, d0.x, 0x07060302u);
                blA.u[jj] = __builtin_amdgcn_perm(d1.y, d0.y, 0x05040100u);
                blB.u[jj] = __builtin_amdgcn_perm(d1.y, d0.y, 0x07060302u);
            }
            #pragma unroll
            for (int hh2 = 0; hh2 < 2; hh2++) {
                const bf16x8 bh = hh2 ? bhB.v : bhA.v;
                const bf16x8 bl = hh2 ? blB.v : blA.v;
                f32x4 o = {0.f, 0.f, 0.f, 0.f};
                o = __builtin_amdgcn_mfma_f32_16x16x32_bf16(al[ei].v, bh, o, 0, 0, 0);
                o = __builtin_amdgcn_mfma_f32_16x16x32_bf16(ah[ei].v, bl, o, 0, 0, 0);
                o = __builtin_amdgcn_mfma_f32_16x16x32_bf16(ah[ei].v, bh, o, 0, 0, 0);
                const int cblk = (hh2 * 16 + low) * 2 + (quad >> 1);
                const int hw = cblk * 128 + ((ee ^ (cblk & 15)) * 8) + (quad & 1) * 4;
                const unsigned short h0 = f2bf(o[0]), h1 = f2bf(o[1]);
                const unsigned short h2 = f2bf(o[2]), h3 = f2bf(o[3]);
                uint2 ph;
                ph.x = (unsigned int)h0 | ((unsigned int)h1 << 16);
                ph.y = (unsigned int)h2 | ((unsigned int)h3 << 16);
                *(uint2*)&wfA_hi[hw] = ph;
                uint2 pl;
                pl.x = (unsigned int)f2bf(o[0] - bf2f(h0)) |
                       ((unsigned int)f2bf(o[1] - bf2f(h1)) << 16);
                pl.y = (unsigned int)f2bf(o[2] - bf2f(h2)) |
                       ((unsigned int)f2bf(o[3] - bf2f(h3)) << 16);
                *(uint2*)&wfA_lo[hw] = pl;
            }
        }
        __syncthreads();
        // ---- phase C: feat0[16e x 48o] accumulate over this chunk ----
        if (wave < 6) {
            const bf16x8* Bh = (const bf16x8*)dwB_hi;
            const bf16x8* Bl = (const bf16x8*)dwB_lo;
            #pragma unroll 4
            for (int ktl = half * 8; ktl < half * 8 + 8; ktl++) {
                const int cblk = ktl * 4 + quad;
                const int hw = cblk * 128 + ((low ^ (cblk & 15)) * 8);
                bf16x8 a_h = *(const bf16x8*)&wfA_hi[hw];
                bf16x8 a_l = *(const bf16x8*)&wfA_lo[hw];
                const int ktg = c * 16 + ktl;
                bf16x8 b_h = Bh[(nt * 64 + ktg) * 64 + lane];
                bf16x8 b_l = Bl[(nt * 64 + ktg) * 64 + lane];
                acc = __builtin_amdgcn_mfma_f32_16x16x32_bf16(a_l, b_h, acc, 0, 0, 0);
                acc = __builtin_amdgcn_mfma_f32_16x16x32_bf16(a_h, b_l, acc, 0, 0, 0);
                acc = __builtin_amdgcn_mfma_f32_16x16x32_bf16(a_h, b_h, acc, 0, 0, 0);
            }
        } else if (c == 0 && wave == 6 && lane < 48) {
            defkp[(qbase + lane / 3) * 45 + (lane % 3)] = kp_s[lane % 3];
        }
        __syncthreads();
    }

    if (wave < 6 && half == 1) cred[nt * 64 + lane] = acc;
    __syncthreads();
    if (wave < 6 && half == 0) {
        f32x4 o2 = cred[nt * 64 + lane];
        acc[0] += o2[0]; acc[1] += o2[1]; acc[2] += o2[2]; acc[3] += o2[3];
        const int o = nt * 16 + low;
        if (o < OD) {
            const float bo = bias[o] + kp_s[3 + o];
            #pragma unroll
            for (int r = 0; r < 4; r++) {
                const int ee = quad * 4 + r;          // full 16 rows now real
                defkp[(qbase + ee) * 45 + 3 + o] = bo + acc[r];
            }
        }
    }
}

// ------------------------- stage 2 (bf16 MFMA): deformable conv -------------------------
// E=32 queries/block, 512 threads (8 waves). f-chunked (4 chunks of 32) so the
// wf1 buffer is 32 KB. Each wave: 2 nt columns x 2 e-tiles -> B-frag loads are
// shared across two accumulators (Bsw L2 traffic halved per query).
// wfA layout: cblk = c_local>>3 (0..63), slot = e ^ (cblk&31),
//             hw = cblk*256 + slot*8 + (c_local&7); reads conflict-free.
__global__ __launch_bounds__(512, 4)
void k2_deform(const float* __restrict__ query, const float* __restrict__ support,
               const int* __restrict__ neighbors, const unsigned int* __restrict__ fp2,
               const unsigned short* __restrict__ Bsw, const float* __restrict__ defkp,
               float* __restrict__ out)
{
    __shared__ unsigned short wfA[16384];                 // 32 KB
    __shared__ float relx[1024], rely[1024], relz[1024];  // 12288 B
    __shared__ float dk_s[32 * 45];                       // 5760 B
    __shared__ unsigned short nbr_s[1024];                // 2048 B (idx < 16384)

    const int t = threadIdx.x;
    const int qbase = blockIdx.x * 32;

    for (int i = t; i < 32 * 45; i += 512) dk_s[i] = defkp[qbase * 45 + i];
    #pragma unroll
    for (int ii = 0; ii < 2; ii++) {
        const int i = ii * 512 + t;
        const int e = i >> 5, n = i & 31;
        const int q = qbase + e;
        const int idx = neighbors[q * NN + n];
        nbr_s[i] = (unsigned short)idx;
        relx[i] = support[idx * 3 + 0] - query[q * 3 + 0];
        rely[i] = support[idx * 3 + 1] - query[q * 3 + 1];
        relz[i] = support[idx * 3 + 2] - query[q * 3 + 2];
    }
    __syncthreads();

    const int wave = t >> 6, lane = t & 63;
    const int quad = lane >> 4, low = lane & 15;
    const int ee0 = wave * 4;
    const int kb = (low < KPN) ? low * 3 : 0;

    // hoisted A-fragments (w1^T) for this wave's four queries
    U8 af[4];
    #pragma unroll
    for (int ei = 0; ei < 4; ei++) {
        const int ee = ee0 + ei;
        const float kx = dk_s[ee * 45 + kb + 0];
        const float ky = dk_s[ee * 45 + kb + 1];
        const float kz = dk_s[ee * 45 + kb + 2];
        #pragma unroll
        for (int j = 0; j < 8; j++) {
            const int ni = ee * 32 + quad * 8 + j;
            const float dx = relx[ni] - kx;
            const float dy = rely[ni] - ky;
            const float dz = relz[ni] - kz;
            const float d = sqrtf(dx * dx + dy * dy + dz * dz);
            float w = 1.0f - d * INV_EXT;
            w = (low < KPN && w > 0.f) ? w : 0.f;
            af[ei].u[j] = f2bf(w);
        }
    }

    f32x4 acc00 = {0,0,0,0}, acc01 = {0,0,0,0};
    f32x4 acc10 = {0,0,0,0}, acc11 = {0,0,0,0};
    const int nt0 = wave * 2, nt1 = nt0 + 1;
    const bf16x8* Bp = (const bf16x8*)Bsw;

    for (int c = 0; c < 4; c++) {
        // ---- wf1 chunk for f in [c*32, c*32+32) ----
        #pragma unroll
        for (int ei = 0; ei < 4; ei++) {
            const int ee = ee0 + ei;
            union { unsigned int u[4]; bf16x8 v; } bA, bB;
            #pragma unroll
            for (int jj = 0; jj < 4; jj++) {
                const int r0 = nbr_s[ee * 32 + quad * 8 + 2 * jj];
                const int r1 = nbr_s[ee * 32 + quad * 8 + 2 * jj + 1];
                const unsigned int d0 = fp2[r0 * 64 + c * 16 + low];
                const unsigned int d1 = fp2[r1 * 64 + c * 16 + low];
                bA.u[jj] = __builtin_amdgcn_perm(d1, d0, 0x05040100u);
                bB.u[jj] = __builtin_amdgcn_perm(d1, d0, 0x07060302u);
            }
            #pragma unroll
            for (int hh2 = 0; hh2 < 2; hh2++) {
                const bf16x8 b = hh2 ? bB.v : bA.v;
                f32x4 o = {0.f, 0.f, 0.f, 0.f};
                o = __builtin_amdgcn_mfma_f32_16x16x32_bf16(af[ei].v, b, o, 0, 0, 0);
                const int cblk = (hh2 * 16 + low) * 2 + (quad >> 1);
                const int hw = cblk * 256 + ((ee ^ (cblk & 31)) * 8) + (quad & 1) * 4;
                uint2 ph;
                ph.x = (unsigned int)f2bf(o[0]) | ((unsigned int)f2bf(o[1]) << 16);
                ph.y = (unsigned int)f2bf(o[2]) | ((unsigned int)f2bf(o[3]) << 16);
                *(uint2*)&wfA[hw] = ph;
            }
        }
        __syncthreads();
        // ---- GEMM2 chunk: out[32 x 256] += wf1_chunk * Bsw_chunk ----
        #pragma unroll 4
        for (int ktl = 0; ktl < 16; ktl++) {
            const int cblk = ktl * 4 + quad;
            const int s0 = (low ^ (cblk & 31)) * 8;
            const int s1 = ((16 + low) ^ (cblk & 31)) * 8;
            bf16x8 a0 = *(const bf16x8*)&wfA[cblk * 256 + s0];
            bf16x8 a1 = *(const bf16x8*)&wfA[cblk * 256 + s1];
            const int ktg = c * 16 + ktl;
            bf16x8 b0 = Bp[(nt0 * 64 + ktg) * 64 + lane];
            bf16x8 b1 = Bp[(nt1 * 64 + ktg) * 64 + lane];
            acc00 = __builtin_amdgcn_mfma_f32_16x16x32_bf16(a0, b0, acc00, 0, 0, 0);
            acc01 = __builtin_amdgcn_mfma_f32_16x16x32_bf16(a0, b1, acc01, 0, 0, 0);
            acc10 = __builtin_amdgcn_mfma_f32_16x16x32_bf16(a1, b0, acc10, 0, 0, 0);
            acc11 = __builtin_amdgcn_mfma_f32_16x16x32_bf16(a1, b1, acc11, 0, 0, 0);
        }
        __syncthreads();
    }

    #pragma unroll
    for (int r = 0; r < 4; r++) {
        const int e0 = quad * 4 + r;
        out[(qbase + e0) * FO + nt0 * 16 + low] = acc00[r];
        out[(qbase + e0) * FO + nt1 * 16 + low] = acc01[r];
        out[(qbase + 16 + e0) * FO + nt0 * 16 + low] = acc10[r];
        out[(qbase + 16 + e0) * FO + nt1 * 16 + low] = acc11[r];
    }
}

// -------------------------------------------------------------------------
extern "C" void kernel_launch(void* const* d_in, const int* in_sizes, int n_in,
                              void* d_out, int out_size, void* d_ws, size_t ws_size,
                              hipStream_t stream) {
    const float* query     = (const float*)d_in[0];
    const float* support   = (const float*)d_in[1];
    const int*   neighbors = (const int*)  d_in[2];
    const float* features  = (const float*)d_in[3];
    const float* kpoints   = (const float*)d_in[4];
    const float* weight    = (const float*)d_in[5];
    const float* dweight   = (const float*)d_in[6];
    const float* bias      = (const float*)d_in[7];
    float*       out       = (float*)d_out;

    char* ws = (char*)d_ws;
    unsigned int*   fp1  = (unsigned int*)(ws + WS_FP1);
    unsigned int*   fp2  = (unsigned int*)(ws + WS_FP2);
    unsigned short* Bsw  = (unsigned short*)(ws + WS_BSW);
    unsigned short* dwBh = (unsigned short*)(ws + WS_DWBH);
    unsigned short* dwBl = (unsigned short*)(ws + WS_DWBL);
    float*          defkp = (float*)(ws + WS_DEFKP);

    pre_all<<<4400, 256, 0, stream>>>(features, fp1, fp2, weight, Bsw,
                                      dweight, dwBh, dwBl);
    k1_offsets<<<NQ / 16, 512, 0, stream>>>(query, support, neighbors, fp1,
                                            kpoints, dwBh, dwBl, bias, defkp);
    k2_deform<<<NQ / 32, 512, 0, stream>>>(query, support, neighbors, fp2,
                                           Bsw, defkp, out);
}